// Round 9
// baseline (301.000 us; speedup 1.0000x reference)
//
#include <hip/hip_runtime.h>
#include <hip/hip_bf16.h>
#include <stdint.h>

#define SEQ   2048
#define BATCH 2
#define DIM   1024
#define NHEAD 16
#define HD    64
#define NT    (BATCH*SEQ)   // 4096 tokens
#define N3    (3*DIM)       // 3072
#define QSCALE 0.180336881f // 0.125 * log2(e)

typedef __attribute__((ext_vector_type(4)))  float f32x4;
typedef __attribute__((ext_vector_type(16))) float f32x16;
typedef __attribute__((ext_vector_type(8)))  short s16x8;
typedef __attribute__((ext_vector_type(4)))  unsigned short u16x4;
typedef __attribute__((ext_vector_type(4)))  unsigned int u32x4;

__device__ __forceinline__ unsigned short f2bf(float x){
  union { float f; uint32_t u; } v; v.f = x;
  return (unsigned short)((v.u + 0x7fffu + ((v.u >> 16) & 1u)) >> 16);
}
__device__ __forceinline__ unsigned int cvtpk(float lo, float hi){
  unsigned int r;
  asm("v_cvt_pk_bf16_f32 %0, %1, %2" : "=v"(r) : "v"(lo), "v"(hi));
  return r;
}
__device__ __forceinline__ void gload16(const void* g, void* l){
  __builtin_amdgcn_global_load_lds((const __attribute__((address_space(1))) void*)g,
                                   (__attribute__((address_space(3))) void*)l, 16, 0, 0);
}
__device__ __forceinline__ f32x16 zero16(){
  f32x16 z;
#pragma unroll
  for (int i=0;i<16;i++) z[i]=0.f;
  return z;
}
#define MFMA(a,b,c)   __builtin_amdgcn_mfma_f32_16x16x32_bf16((a),(b),(c),0,0,0)
#define MFMA32(a,b,c) __builtin_amdgcn_mfma_f32_32x32x16_bf16((a),(b),(c),0,0,0)

// ---------------- RoPE cos/sin table: cs[t*32+i] = (cos, sin) ----------------
__global__ __launch_bounds__(256) void k_ropetab(float2* __restrict__ cs){
  const int idx = blockIdx.x*256 + threadIdx.x;   // 65536 entries
  const int t = idx >> 5, i = idx & 31;
  const float ang = (float)t * exp2f((float)i * -0.41524101186f); // 10000^(-i/32)
  float sn, c; sincosf(ang, &sn, &c);
  cs[idx] = make_float2(c, sn);
}

// ---------------- convert fp32 -> bf16 ----------------
__global__ __launch_bounds__(256) void k_tobf(const float* __restrict__ in,
                                              unsigned short* __restrict__ o, int n4){
  int i = blockIdx.x*256 + threadIdx.x;
  if (i >= n4) return;
  f32x4 v = ((const f32x4*)in)[i];
  u16x4 h;
#pragma unroll
  for (int e=0;e<4;e++) h[e] = f2bf(v[e]);
  ((u16x4*)o)[i] = h;
}

// ---------------- transpose + convert: in[R][C] f32 -> outT[C][R] bf16 ----------------
__global__ void k_transT(const float* __restrict__ in,
                         unsigned short* __restrict__ oT, int R, int C){
  __shared__ float t[32][33];
  int c0 = blockIdx.x*32, r0 = blockIdx.y*32;
  int tx = threadIdx.x, ty = threadIdx.y;
#pragma unroll
  for (int j=0;j<32;j+=8) t[ty+j][tx] = in[(size_t)(r0+ty+j)*C + c0+tx];
  __syncthreads();
#pragma unroll
  for (int j=0;j<32;j+=8)
    oT[(size_t)(c0+ty+j)*R + r0+tx] = f2bf(t[tx][ty+j]);
}

// ---------------- transpose V: [bh][t][d] -> [bh][d][t] ----------------
__global__ __launch_bounds__(256) void k_transV(const unsigned short* __restrict__ v,
                                                unsigned short* __restrict__ vT){
  __shared__ unsigned short t[64][65];
  const int bh = blockIdx.y, t0 = blockIdx.x*64;
  const int tid = threadIdx.x;
  const size_t base = (size_t)bh*SEQ*HD;
  const int r = tid>>3, c = (tid&7)*8;
#pragma unroll
  for (int it=0; it<2; ++it){
    const int row = it*32 + r;
    s16x8 val = *(const s16x8*)(v + base + (size_t)(t0+row)*HD + c);
#pragma unroll
    for (int e=0;e<8;e++) t[row][c+e] = (unsigned short)val[e];
  }
  __syncthreads();
#pragma unroll
  for (int it=0; it<2; ++it){
    const int drow = it*32 + r;
    s16x8 o;
#pragma unroll
    for (int e=0;e<8;e++) o[e] = (short)t[c+e][drow];
    *(s16x8*)(vT + base + (size_t)drow*SEQ + t0 + c) = o;
  }
}

// ---------------- plain bf16 QKV GEMM: C[M,3072] = A[M,1024]*B^T + bias, RoPE, scatter ----
__global__ __launch_bounds__(256) void k_gemm(
    const unsigned short* __restrict__ A, const unsigned short* __restrict__ B,
    const float* __restrict__ bias, const float2* __restrict__ cstab,
    unsigned short* __restrict__ qb, unsigned short* __restrict__ kbp,
    unsigned short* __restrict__ vbp){
  __shared__ unsigned short sA[128*32];
  __shared__ unsigned short sB[128*32];
  const int tid = threadIdx.x;
  const int w = tid>>6, lane = tid&63;
  const int lr = lane&15, lk = lane>>4;
  const int wm = (w>>1)*64, wn = (w&1)*64;
  const int m0 = blockIdx.y*128, n0 = blockIdx.x*128;

  f32x4 acc[4][4];
#pragma unroll
  for (int m=0;m<4;m++)
#pragma unroll
    for (int n=0;n<4;n++) acc[m][n] = (f32x4){0.f,0.f,0.f,0.f};

  const int srow  = lane>>2;       // row within 16-row chunk
  const int sbyte = (lane&3)*16;   // byte col within 64B row

  for (int kt=0; kt<1024/32; ++kt){
    const int k0 = kt*32;
#pragma unroll
    for (int cc=0; cc<2; ++cc){
      const int chunk = w*2+cc;
      const int row = chunk*16 + srow;
      gload16((const char*)A + ((size_t)(m0+row)*1024 + k0)*2 + sbyte, (char*)sA + chunk*1024);
      gload16((const char*)B + ((size_t)(n0+row)*1024 + k0)*2 + sbyte, (char*)sB + chunk*1024);
    }
    __syncthreads();

    s16x8 ah[4], bh[4];
#pragma unroll
    for (int m=0;m<4;m++)
      ah[m] = *(const s16x8*)((const char*)sA + (wm + m*16 + lr)*64 + lk*16);
#pragma unroll
    for (int n=0;n<4;n++)
      bh[n] = *(const s16x8*)((const char*)sB + (wn + n*16 + lr)*64 + lk*16);
#pragma unroll
    for (int m=0;m<4;m++)
#pragma unroll
      for (int n=0;n<4;n++)
        acc[m][n] = MFMA(ah[m], bh[n], acc[m][n]);
    __syncthreads();
  }

#pragma unroll
  for (int m=0;m<4;m++)
#pragma unroll
    for (int n=0;n<4;n++)
#pragma unroll
      for (int r=0;r<4;r++){
        const int gm = m0 + wm + m*16 + lk*4 + r;
        const int gn = n0 + wn + n*16 + lr;
        float val = acc[m][n][r] + bias[gn];
        const int three = gn>>10, rem = gn&1023, h = rem>>6, d = rem&63;
        const int b = gm>>11, t = gm&2047;
        const float partner = __shfl_xor(val, 1);
        const size_t dst = ((size_t)(b*NHEAD + h))*SEQ*HD + (size_t)t*HD + d;
        if (three < 2){
          const float2 cs = cstab[t*32 + (d>>1)];
          float o;
          if (d & 1) o = partner*cs.y + val*cs.x;   // im' = re*sin + im*cos
          else       o = val*cs.x - partner*cs.y;   // re' = re*cos - im*sin
          if (three==0) qb[dst] = f2bf(o*QSCALE);
          else          kbp[dst] = f2bf(o);
        } else {
          vbp[dst] = f2bf(val);
        }
      }
}

// ---------------- proj GEMM: out[4096,1024] = A[4096,1024]*B^T + bias (fp32 out) ----------------
__global__ __launch_bounds__(256) void k_gemmP(
    const unsigned short* __restrict__ A, const unsigned short* __restrict__ B,
    const float* __restrict__ bias, float* __restrict__ outp){
  __shared__ unsigned short sA[128*32];
  __shared__ unsigned short sB[64*32];
  const int tid = threadIdx.x;
  const int w = tid>>6, lane = tid&63;
  const int lr = lane&15, lk = lane>>4;
  const int m0 = blockIdx.y*128, n0 = blockIdx.x*64;

  f32x4 acc[2][4];
#pragma unroll
  for (int m=0;m<2;m++)
#pragma unroll
    for (int n=0;n<4;n++) acc[m][n] = (f32x4){0.f,0.f,0.f,0.f};

  const int srow  = lane>>2;
  const int sbyte = (lane&3)*16;

  for (int kt=0; kt<1024/32; ++kt){
    const int k0 = kt*32;
#pragma unroll
    for (int cc=0; cc<2; ++cc){
      const int chunk = w*2+cc;
      const int row = chunk*16 + srow;
      gload16((const char*)A + ((size_t)(m0+row)*1024 + k0)*2 + sbyte,
              (char*)sA + chunk*1024);
    }
    {
      const int row = w*16 + srow;
      gload16((const char*)B + ((size_t)(n0+row)*1024 + k0)*2 + sbyte,
              (char*)sB + w*1024);
    }
    __syncthreads();

    s16x8 ah[2], bh[4];
#pragma unroll
    for (int m=0;m<2;m++)
      ah[m] = *(const s16x8*)((const char*)sA + (w*32 + m*16 + lr)*64 + lk*16);
#pragma unroll
    for (int n=0;n<4;n++)
      bh[n] = *(const s16x8*)((const char*)sB + (n*16 + lr)*64 + lk*16);
#pragma unroll
    for (int m=0;m<2;m++)
#pragma unroll
      for (int n=0;n<4;n++)
        acc[m][n] = MFMA(ah[m], bh[n], acc[m][n]);
    __syncthreads();
  }

#pragma unroll
  for (int m=0;m<2;m++)
#pragma unroll
    for (int n=0;n<4;n++)
#pragma unroll
      for (int r=0;r<4;r++){
        const int gm = m0 + w*32 + m*16 + lk*4 + r;
        const int gn = n0 + n*16 + lr;
        outp[(size_t)gm*DIM + gn] = acc[m][n][r] + bias[gn];
      }
}

// ---------------- flash attention, KV-split 2: partial O (f32) + (m,l) per row ----------------
// grid 1024: work = (bhqt, half); 4 waves/block, wave = 32 q rows, kv range = half*1024..+1024
// All cross-lane ops via proven __shfl_xor(32) (permlane32_swap builtin failed r8 — do not retry)
__global__ __launch_bounds__(256, 4) void k_attn(const unsigned short* __restrict__ qb,
                                                 const unsigned short* __restrict__ kb,
                                                 const unsigned short* __restrict__ vTb,
                                                 float* __restrict__ po,
                                                 float2* __restrict__ ml){
  const int flat = blockIdx.x;
  const int work = (flat & 7)*128 + (flat >> 3);   // XCD swizzle
  const int bhqt = work >> 1, half = work & 1;
  const int bh = bhqt >> 4, qt = bhqt & 15;
  const int wid = threadIdx.x >> 6, lane = threadIdx.x & 63;
  const int col = lane & 31, hi = lane >> 5;
  const size_t base = (size_t)bh*SEQ*HD;
  const int q0 = qt*128 + wid*32;
  const unsigned short* kbase = kb + base;
  const unsigned short* vbase = vTb + base;

  s16x8 qf[4];
  {
    const unsigned short* qp = qb + base + (size_t)(q0+col)*HD + hi*8;
#pragma unroll
    for (int hb=0;hb<4;hb++) qf[hb] = *(const s16x8*)(qp + hb*16);
  }

  f32x16 o0 = zero16(), o1 = zero16();
  float m = -INFINITY, l = 0.f;

  const int kvbeg = half*1024;
  for (int kv0 = kvbeg; kv0 < kvbeg+1024; kv0 += 64){
    s16x8 kf0[4], kf1[4];
    {
      const unsigned short* kp = kbase + (size_t)(kv0+col)*HD + hi*8;
#pragma unroll
      for (int hb=0;hb<4;hb++){
        kf0[hb] = *(const s16x8*)(kp + hb*16);
        kf1[hb] = *(const s16x8*)(kp + 32*HD + hb*16);
      }
    }
    f32x16 a0 = zero16(), a1 = zero16();
    __builtin_amdgcn_s_setprio(1);
#pragma unroll
    for (int hb=0;hb<4;hb++){
      a0 = MFMA32(kf0[hb], qf[hb], a0);
      a1 = MFMA32(kf1[hb], qf[hb], a1);
    }
    __builtin_amdgcn_s_setprio(0);

    s16x8 vf0[4], vf1[4];
    {
      const unsigned short* vp = vbase + (size_t)col*SEQ + kv0 + hi*8;
#pragma unroll
      for (int mk=0;mk<4;mk++){
        vf0[mk] = *(const s16x8*)(vp + mk*16);
        vf1[mk] = *(const s16x8*)(vp + (size_t)32*SEQ + mk*16);
      }
    }

    // in-register online softmax (log2 domain; scale folded into Q)
    float pm0 = fmaxf(a0[0], a0[1]), pm1 = fmaxf(a0[2], a0[3]);
#pragma unroll
    for (int i=4;i<16;i+=2){ pm0 = fmaxf(pm0, a0[i]); pm1 = fmaxf(pm1, a0[i+1]); }
#pragma unroll
    for (int i=0;i<16;i+=2){ pm0 = fmaxf(pm0, a1[i]); pm1 = fmaxf(pm1, a1[i+1]); }
    float pm = fmaxf(pm0, pm1);
    pm = fmaxf(pm, __shfl_xor(pm, 32));

    if (!__all(pm - m <= 8.0f)){   // T13 defer-max
      const float mn = fmaxf(m, pm);
      const float al = __builtin_amdgcn_exp2f(m - mn);
      l *= al;
#pragma unroll
      for (int i=0;i<16;i++){ o0[i] *= al; o1[i] *= al; }
      m = mn;
    }
#pragma unroll
    for (int i=0;i<16;i++){
      a0[i] = __builtin_amdgcn_exp2f(a0[i] - m);
      a1[i] = __builtin_amdgcn_exp2f(a1[i] - m);
    }
    float rs = 0.f;
#pragma unroll
    for (int i=0;i<16;i++) rs += a0[i] + a1[i];
    rs += __shfl_xor(rs, 32);
    l += rs;

    // P -> A-fragments: cvt_pk + shfl_xor(32) half-exchange (round-4/6/7 proven form)
    unsigned int pfd[4][4];
#pragma unroll
    for (int kb2=0; kb2<4; kb2++){
      float cc[8];
#pragma unroll
      for (int j=0;j<8;j++) cc[j] = (kb2<2) ? a0[(kb2&1)*8+j] : a1[(kb2&1)*8+j];
      unsigned int lo0 = cvtpk(cc[0],cc[1]), lo1 = cvtpk(cc[2],cc[3]);
      unsigned int h0  = cvtpk(cc[4],cc[5]), h1  = cvtpk(cc[6],cc[7]);
      unsigned int sl0 = (unsigned int)__shfl_xor((int)lo0, 32);
      unsigned int sl1 = (unsigned int)__shfl_xor((int)lo1, 32);
      unsigned int sh0 = (unsigned int)__shfl_xor((int)h0, 32);
      unsigned int sh1 = (unsigned int)__shfl_xor((int)h1, 32);
      pfd[kb2][0] = hi ? sh0 : lo0;
      pfd[kb2][1] = hi ? sh1 : lo1;
      pfd[kb2][2] = hi ? h0  : sl0;
      pfd[kb2][3] = hi ? h1  : sl1;
    }

    __builtin_amdgcn_s_setprio(1);
#pragma unroll
    for (int mk=0;mk<4;mk++){
      u32x4 dd = {pfd[mk][0], pfd[mk][1], pfd[mk][2], pfd[mk][3]};
      s16x8 pa = __builtin_bit_cast(s16x8, dd);
      o0 = MFMA32(pa, vf0[mk], o0);
      o1 = MFMA32(pa, vf1[mk], o1);
    }
    __builtin_amdgcn_s_setprio(0);
  }

  // epilogue: raw partials; combine kernel applies 1/l
#pragma unroll
  for (int r=0;r<16;r++){
    const int qloc = (r&3) + 8*(r>>2) + 4*hi;
    const size_t orow = ((size_t)work*128 + wid*32 + qloc)*64;
    po[orow + col]      = o0[r];
    po[orow + 32 + col] = o1[r];
  }
  if (hi == 0)
    ml[(size_t)work*128 + wid*32 + col] = make_float2(m, l);
}

// ---------------- combine: merge the two kv-halves, write bf16 proj input ----------------
__global__ __launch_bounds__(256) void k_comb(const float* __restrict__ po,
                                              const float2* __restrict__ ml,
                                              unsigned short* __restrict__ ao){
  const int idx = blockIdx.x*256 + threadIdx.x;   // 65536 rows * 16 chunks
  const int row = idx >> 4;            // bhqt*128 + qrow
  const int dc  = (idx & 15) * 4;
  const int bhqt = row >> 7, qrow = row & 127;
  const float2 ml0 = ml[(size_t)(bhqt*2+0)*128 + qrow];
  const float2 ml1 = ml[(size_t)(bhqt*2+1)*128 + qrow];
  const float M = fmaxf(ml0.x, ml1.x);
  const float w0 = __builtin_amdgcn_exp2f(ml0.x - M);
  const float w1 = __builtin_amdgcn_exp2f(ml1.x - M);
  const float inv = 1.0f / (ml0.y*w0 + ml1.y*w1);
  const f32x4 a = *(const f32x4*)(po + ((size_t)(bhqt*2+0)*128 + qrow)*64 + dc);
  const f32x4 b4 = *(const f32x4*)(po + ((size_t)(bhqt*2+1)*128 + qrow)*64 + dc);
  const int bh = bhqt >> 4, qt = bhqt & 15;
  const int b = bh >> 4, h = bh & 15;
  const int tq = qt*128 + qrow;
  u16x4 r;
#pragma unroll
  for (int e=0;e<4;e++) r[e] = f2bf((a[e]*w0 + b4[e]*w1) * inv);
  *(u16x4*)(ao + ((size_t)(b*SEQ + tq))*DIM + h*HD + dc) = r;
}

extern "C" void kernel_launch(void* const* d_in, const int* in_sizes, int n_in,
                              void* d_out, int out_size, void* d_ws, size_t ws_size,
                              hipStream_t stream){
  const float* x     = (const float*)d_in[0];
  const float* Wqkv  = (const float*)d_in[1];
  const float* bqkv  = (const float*)d_in[2];
  const float* Wproj = (const float*)d_in[3];
  const float* bproj = (const float*)d_in[4];
  float* out = (float*)d_out;

  char* ws = (char*)d_ws;
  size_t off = 0;
  auto alloc = [&](size_t bytes)->char*{
    char* p = ws + off; off += (bytes + 255) & ~(size_t)255; return p;
  };
  unsigned short* xb    = (unsigned short*)alloc((size_t)NT*DIM*2);
  unsigned short* wqT   = (unsigned short*)alloc((size_t)N3*DIM*2);
  unsigned short* wpT   = (unsigned short*)alloc((size_t)DIM*DIM*2);
  unsigned short* q_bf  = (unsigned short*)alloc((size_t)NT*DIM*2);
  unsigned short* k_bf  = (unsigned short*)alloc((size_t)NT*DIM*2);
  unsigned short* v_bf  = (unsigned short*)alloc((size_t)NT*DIM*2);
  unsigned short* vT_bf = (unsigned short*)alloc((size_t)NT*DIM*2);
  unsigned short* ao_bf = (unsigned short*)alloc((size_t)NT*DIM*2);
  float*          po    = (float*)alloc((size_t)1024*128*64*sizeof(float));
  float2*         mlb   = (float2*)alloc((size_t)1024*128*sizeof(float2));
  float2*         cstab = (float2*)alloc((size_t)SEQ*32*sizeof(float2));

  k_ropetab<<<SEQ*32/256, 256, 0, stream>>>(cstab);
  k_tobf<<<(NT*DIM/4)/256, 256, 0, stream>>>(x, xb, NT*DIM/4);
  k_transT<<<dim3(N3/32, DIM/32), dim3(32,8), 0, stream>>>(Wqkv, wqT, DIM, N3);
  k_transT<<<dim3(DIM/32, DIM/32), dim3(32,8), 0, stream>>>(Wproj, wpT, DIM, DIM);
  k_gemm<<<dim3(N3/128, NT/128), 256, 0, stream>>>(xb, wqT, bqkv, cstab, q_bf, k_bf, v_bf);
  k_transV<<<dim3(SEQ/64, BATCH*NHEAD), 256, 0, stream>>>(v_bf, vT_bf);
  k_attn<<<dim3(1024), 256, 0, stream>>>(q_bf, k_bf, vT_bf, po, mlb);
  k_comb<<<(65536*16)/256, 256, 0, stream>>>(po, mlb, ao_bf);
  k_gemmP<<<dim3(DIM/64, NT/128), 256, 0, stream>>>(ao_bf, wpT, bproj, out);
}

// Round 11
// 285.978 us; speedup vs baseline: 1.0525x; 1.0525x over previous
//
#include <hip/hip_runtime.h>
#include <hip/hip_bf16.h>
#include <stdint.h>

#define SEQ   2048
#define BATCH 2
#define DIM   1024
#define NHEAD 16
#define HD    64
#define NT    (BATCH*SEQ)   // 4096 tokens
#define N3    (3*DIM)       // 3072
#define QSCALE 0.180336881f // 0.125 * log2(e)

typedef __attribute__((ext_vector_type(4)))  float f32x4;
typedef __attribute__((ext_vector_type(16))) float f32x16;
typedef __attribute__((ext_vector_type(8)))  short s16x8;
typedef __attribute__((ext_vector_type(4)))  unsigned short u16x4;
typedef __attribute__((ext_vector_type(4)))  unsigned int u32x4;

__device__ __forceinline__ unsigned short f2bf(float x){
  union { float f; uint32_t u; } v; v.f = x;
  return (unsigned short)((v.u + 0x7fffu + ((v.u >> 16) & 1u)) >> 16);
}
__device__ __forceinline__ unsigned int cvtpk(float lo, float hi){
  unsigned int r;
  asm("v_cvt_pk_bf16_f32 %0, %1, %2" : "=v"(r) : "v"(lo), "v"(hi));
  return r;
}
__device__ __forceinline__ void gload16(const void* g, void* l){
  __builtin_amdgcn_global_load_lds((const __attribute__((address_space(1))) void*)g,
                                   (__attribute__((address_space(3))) void*)l, 16, 0, 0);
}
__device__ __forceinline__ f32x16 zero16(){
  f32x16 z;
#pragma unroll
  for (int i=0;i<16;i++) z[i]=0.f;
  return z;
}
#define MFMA(a,b,c)   __builtin_amdgcn_mfma_f32_16x16x32_bf16((a),(b),(c),0,0,0)
#define MFMA32(a,b,c) __builtin_amdgcn_mfma_f32_32x32x16_bf16((a),(b),(c),0,0,0)

// ---------------- RoPE cos/sin table: cs[t*32+i] = (cos, sin) ----------------
__global__ __launch_bounds__(256) void k_ropetab(float2* __restrict__ cs){
  const int idx = blockIdx.x*256 + threadIdx.x;   // 65536 entries
  const int t = idx >> 5, i = idx & 31;
  const float ang = (float)t * exp2f((float)i * -0.41524101186f); // 10000^(-i/32)
  float sn, c; sincosf(ang, &sn, &c);
  cs[idx] = make_float2(c, sn);
}

// ---------------- convert fp32 -> bf16 ----------------
__global__ __launch_bounds__(256) void k_tobf(const float* __restrict__ in,
                                              unsigned short* __restrict__ o, int n4){
  int i = blockIdx.x*256 + threadIdx.x;
  if (i >= n4) return;
  f32x4 v = ((const f32x4*)in)[i];
  u16x4 h;
#pragma unroll
  for (int e=0;e<4;e++) h[e] = f2bf(v[e]);
  ((u16x4*)o)[i] = h;
}

// ---------------- transpose + convert: in[R][C] f32 -> outT[C][R] bf16 ----------------
__global__ void k_transT(const float* __restrict__ in,
                         unsigned short* __restrict__ oT, int R, int C){
  __shared__ float t[32][33];
  int c0 = blockIdx.x*32, r0 = blockIdx.y*32;
  int tx = threadIdx.x, ty = threadIdx.y;
#pragma unroll
  for (int j=0;j<32;j+=8) t[ty+j][tx] = in[(size_t)(r0+ty+j)*C + c0+tx];
  __syncthreads();
#pragma unroll
  for (int j=0;j<32;j+=8)
    oT[(size_t)(c0+ty+j)*R + r0+tx] = f2bf(t[tx][ty+j]);
}

// ---------------- transpose V: [bh][t][d] -> [bh][d][t] ----------------
__global__ __launch_bounds__(256) void k_transV(const unsigned short* __restrict__ v,
                                                unsigned short* __restrict__ vT){
  __shared__ unsigned short t[64][65];
  const int bh = blockIdx.y, t0 = blockIdx.x*64;
  const int tid = threadIdx.x;
  const size_t base = (size_t)bh*SEQ*HD;
  const int r = tid>>3, c = (tid&7)*8;
#pragma unroll
  for (int it=0; it<2; ++it){
    const int row = it*32 + r;
    s16x8 val = *(const s16x8*)(v + base + (size_t)(t0+row)*HD + c);
#pragma unroll
    for (int e=0;e<8;e++) t[row][c+e] = (unsigned short)val[e];
  }
  __syncthreads();
#pragma unroll
  for (int it=0; it<2; ++it){
    const int drow = it*32 + r;
    s16x8 o;
#pragma unroll
    for (int e=0;e<8;e++) o[e] = (short)t[c+e][drow];
    *(s16x8*)(vT + base + (size_t)drow*SEQ + t0 + c) = o;
  }
}

// ---------------- plain bf16 QKV GEMM: C[M,3072] = A[M,1024]*B^T + bias, RoPE, scatter ----
__global__ __launch_bounds__(256) void k_gemm(
    const unsigned short* __restrict__ A, const unsigned short* __restrict__ B,
    const float* __restrict__ bias, const float2* __restrict__ cstab,
    unsigned short* __restrict__ qb, unsigned short* __restrict__ kbp,
    unsigned short* __restrict__ vbp){
  __shared__ unsigned short sA[128*32];
  __shared__ unsigned short sB[128*32];
  const int tid = threadIdx.x;
  const int w = tid>>6, lane = tid&63;
  const int lr = lane&15, lk = lane>>4;
  const int wm = (w>>1)*64, wn = (w&1)*64;
  const int m0 = blockIdx.y*128, n0 = blockIdx.x*128;

  f32x4 acc[4][4];
#pragma unroll
  for (int m=0;m<4;m++)
#pragma unroll
    for (int n=0;n<4;n++) acc[m][n] = (f32x4){0.f,0.f,0.f,0.f};

  const int srow  = lane>>2;       // row within 16-row chunk
  const int sbyte = (lane&3)*16;   // byte col within 64B row

  for (int kt=0; kt<1024/32; ++kt){
    const int k0 = kt*32;
#pragma unroll
    for (int cc=0; cc<2; ++cc){
      const int chunk = w*2+cc;
      const int row = chunk*16 + srow;
      gload16((const char*)A + ((size_t)(m0+row)*1024 + k0)*2 + sbyte, (char*)sA + chunk*1024);
      gload16((const char*)B + ((size_t)(n0+row)*1024 + k0)*2 + sbyte, (char*)sB + chunk*1024);
    }
    __syncthreads();

    s16x8 ah[4], bh[4];
#pragma unroll
    for (int m=0;m<4;m++)
      ah[m] = *(const s16x8*)((const char*)sA + (wm + m*16 + lr)*64 + lk*16);
#pragma unroll
    for (int n=0;n<4;n++)
      bh[n] = *(const s16x8*)((const char*)sB + (wn + n*16 + lr)*64 + lk*16);
#pragma unroll
    for (int m=0;m<4;m++)
#pragma unroll
      for (int n=0;n<4;n++)
        acc[m][n] = MFMA(ah[m], bh[n], acc[m][n]);
    __syncthreads();
  }

#pragma unroll
  for (int m=0;m<4;m++)
#pragma unroll
    for (int n=0;n<4;n++)
#pragma unroll
      for (int r=0;r<4;r++){
        const int gm = m0 + wm + m*16 + lk*4 + r;
        const int gn = n0 + wn + n*16 + lr;
        float val = acc[m][n][r] + bias[gn];
        const int three = gn>>10, rem = gn&1023, h = rem>>6, d = rem&63;
        const int b = gm>>11, t = gm&2047;
        const float partner = __shfl_xor(val, 1);
        const size_t dst = ((size_t)(b*NHEAD + h))*SEQ*HD + (size_t)t*HD + d;
        if (three < 2){
          const float2 cs = cstab[t*32 + (d>>1)];
          float o;
          if (d & 1) o = partner*cs.y + val*cs.x;   // im' = re*sin + im*cos
          else       o = val*cs.x - partner*cs.y;   // re' = re*cos - im*sin
          if (three==0) qb[dst] = f2bf(o*QSCALE);
          else          kbp[dst] = f2bf(o);
        } else {
          vbp[dst] = f2bf(val);
        }
      }
}

// ---------------- proj GEMM: out[4096,1024] = A[4096,1024]*B^T + bias (fp32 out) ----------------
__global__ __launch_bounds__(256) void k_gemmP(
    const unsigned short* __restrict__ A, const unsigned short* __restrict__ B,
    const float* __restrict__ bias, float* __restrict__ outp){
  __shared__ unsigned short sA[128*32];
  __shared__ unsigned short sB[64*32];
  const int tid = threadIdx.x;
  const int w = tid>>6, lane = tid&63;
  const int lr = lane&15, lk = lane>>4;
  const int m0 = blockIdx.y*128, n0 = blockIdx.x*64;

  f32x4 acc[2][4];
#pragma unroll
  for (int m=0;m<2;m++)
#pragma unroll
    for (int n=0;n<4;n++) acc[m][n] = (f32x4){0.f,0.f,0.f,0.f};

  const int srow  = lane>>2;
  const int sbyte = (lane&3)*16;

  for (int kt=0; kt<1024/32; ++kt){
    const int k0 = kt*32;
#pragma unroll
    for (int cc=0; cc<2; ++cc){
      const int chunk = w*2+cc;
      const int row = chunk*16 + srow;
      gload16((const char*)A + ((size_t)(m0+row)*1024 + k0)*2 + sbyte,
              (char*)sA + chunk*1024);
    }
    {
      const int row = w*16 + srow;
      gload16((const char*)B + ((size_t)(n0+row)*1024 + k0)*2 + sbyte,
              (char*)sB + w*1024);
    }
    __syncthreads();

    s16x8 ah[2], bh[4];
#pragma unroll
    for (int m=0;m<2;m++)
      ah[m] = *(const s16x8*)((const char*)sA + (w*32 + m*16 + lr)*64 + lk*16);
#pragma unroll
    for (int n=0;n<4;n++)
      bh[n] = *(const s16x8*)((const char*)sB + (n*16 + lr)*64 + lk*16);
#pragma unroll
    for (int m=0;m<2;m++)
#pragma unroll
      for (int n=0;n<4;n++)
        acc[m][n] = MFMA(ah[m], bh[n], acc[m][n]);
    __syncthreads();
  }

#pragma unroll
  for (int m=0;m<2;m++)
#pragma unroll
    for (int n=0;n<4;n++)
#pragma unroll
      for (int r=0;r<4;r++){
        const int gm = m0 + w*32 + m*16 + lk*4 + r;
        const int gn = n0 + n*16 + lr;
        outp[(size_t)gm*DIM + gn] = acc[m][n][r] + bias[gn];
      }
}

// ---------------- flash attention, KV-split 2, 32-kv tiles (fits 128 unified VGPR @ 4 waves/EU) ----
// grid 1024: work = (bhqt, half); wave = 32 q rows, kv range = half*1024..+1024
// Cross-lane: proven __shfl_xor(32) only (permlane32_swap builtin failed r5/r8 — banned)
__global__ __launch_bounds__(256, 4) void k_attn(const unsigned short* __restrict__ qb,
                                                 const unsigned short* __restrict__ kb,
                                                 const unsigned short* __restrict__ vTb,
                                                 float* __restrict__ po,
                                                 float2* __restrict__ ml){
  const int flat = blockIdx.x;
  const int work = (flat & 7)*128 + (flat >> 3);   // XCD swizzle
  const int bhqt = work >> 1, half = work & 1;
  const int bh = bhqt >> 4, qt = bhqt & 15;
  const int wid = threadIdx.x >> 6, lane = threadIdx.x & 63;
  const int col = lane & 31, hi = lane >> 5;
  const size_t base = (size_t)bh*SEQ*HD;
  const int q0 = qt*128 + wid*32;
  const unsigned short* kbase = kb + base;
  const unsigned short* vbase = vTb + base;

  s16x8 qf[4];
  {
    const unsigned short* qp = qb + base + (size_t)(q0+col)*HD + hi*8;
#pragma unroll
    for (int hb=0;hb<4;hb++) qf[hb] = *(const s16x8*)(qp + hb*16);
  }

  f32x16 o0 = zero16(), o1 = zero16();
  float m = -INFINITY, l = 0.f;

  const int kvbeg = half*1024;
  for (int kv0 = kvbeg; kv0 < kvbeg+1024; kv0 += 32){
    // ---- QK^T for 32 kv rows: a = S^T[kv][q] ----
    f32x16 a = zero16();
    {
      s16x8 kf[4];
      const unsigned short* kp = kbase + (size_t)(kv0+col)*HD + hi*8;
#pragma unroll
      for (int hb=0;hb<4;hb++) kf[hb] = *(const s16x8*)(kp + hb*16);
      __builtin_amdgcn_s_setprio(1);
#pragma unroll
      for (int hb=0;hb<4;hb++) a = MFMA32(kf[hb], qf[hb], a);
      __builtin_amdgcn_s_setprio(0);
    }

    // ---- V^T B-frags for the two K=16 PV steps ----
    s16x8 vf0[2], vf1[2];
    {
      const unsigned short* vp = vbase + (size_t)col*SEQ + kv0 + hi*8;
#pragma unroll
      for (int s=0;s<2;s++){
        vf0[s] = *(const s16x8*)(vp + s*16);
        vf1[s] = *(const s16x8*)(vp + (size_t)32*SEQ + s*16);
      }
    }

    // ---- online softmax on 16 regs (log2 domain; scale folded into Q) ----
    float pm0 = fmaxf(a[0], a[1]), pm1 = fmaxf(a[2], a[3]);
#pragma unroll
    for (int i=4;i<16;i+=2){ pm0 = fmaxf(pm0, a[i]); pm1 = fmaxf(pm1, a[i+1]); }
    float pm = fmaxf(pm0, pm1);
    pm = fmaxf(pm, __shfl_xor(pm, 32));

    if (!__all(pm - m <= 8.0f)){   // T13 defer-max
      const float mn = fmaxf(m, pm);
      const float al = __builtin_amdgcn_exp2f(m - mn);
      l *= al;
#pragma unroll
      for (int i=0;i<16;i++){ o0[i] *= al; o1[i] *= al; }
      m = mn;
    }
#pragma unroll
    for (int i=0;i<16;i++) a[i] = __builtin_amdgcn_exp2f(a[i] - m);
    float rs = 0.f;
#pragma unroll
    for (int i=0;i<16;i++) rs += a[i];
    rs += __shfl_xor(rs, 32);
    l += rs;

    // ---- P -> A-frag (K=16) per step + PV MFMA ----
#pragma unroll
    for (int s=0;s<2;s++){
      unsigned int lo0 = cvtpk(a[s*8+0], a[s*8+1]);
      unsigned int lo1 = cvtpk(a[s*8+2], a[s*8+3]);
      unsigned int h0  = cvtpk(a[s*8+4], a[s*8+5]);
      unsigned int h1  = cvtpk(a[s*8+6], a[s*8+7]);
      unsigned int sl0 = (unsigned int)__shfl_xor((int)lo0, 32);
      unsigned int sl1 = (unsigned int)__shfl_xor((int)lo1, 32);
      unsigned int sh0 = (unsigned int)__shfl_xor((int)h0, 32);
      unsigned int sh1 = (unsigned int)__shfl_xor((int)h1, 32);
      u32x4 dd = {hi ? sh0 : lo0, hi ? sh1 : lo1, hi ? h0 : sl0, hi ? h1 : sl1};
      s16x8 pa = __builtin_bit_cast(s16x8, dd);
      __builtin_amdgcn_s_setprio(1);
      o0 = MFMA32(pa, vf0[s], o0);
      o1 = MFMA32(pa, vf1[s], o1);
      __builtin_amdgcn_s_setprio(0);
    }
  }

  // epilogue: raw partials; combine kernel applies 1/l
#pragma unroll
  for (int r=0;r<16;r++){
    const int qloc = (r&3) + 8*(r>>2) + 4*hi;
    const size_t orow = ((size_t)work*128 + wid*32 + qloc)*64;
    po[orow + col]      = o0[r];
    po[orow + 32 + col] = o1[r];
  }
  if (hi == 0)
    ml[(size_t)work*128 + wid*32 + col] = make_float2(m, l);
}

// ---------------- combine: merge the two kv-halves, write bf16 proj input ----------------
__global__ __launch_bounds__(256) void k_comb(const float* __restrict__ po,
                                              const float2* __restrict__ ml,
                                              unsigned short* __restrict__ ao){
  const int idx = blockIdx.x*256 + threadIdx.x;   // 65536 rows * 16 chunks
  const int row = idx >> 4;            // bhqt*128 + qrow
  const int dc  = (idx & 15) * 4;
  const int bhqt = row >> 7, qrow = row & 127;
  const float2 ml0 = ml[(size_t)(bhqt*2+0)*128 + qrow];
  const float2 ml1 = ml[(size_t)(bhqt*2+1)*128 + qrow];
  const float M = fmaxf(ml0.x, ml1.x);
  const float w0 = __builtin_amdgcn_exp2f(ml0.x - M);
  const float w1 = __builtin_amdgcn_exp2f(ml1.x - M);
  const float inv = 1.0f / (ml0.y*w0 + ml1.y*w1);
  const f32x4 a = *(const f32x4*)(po + ((size_t)(bhqt*2+0)*128 + qrow)*64 + dc);
  const f32x4 b4 = *(const f32x4*)(po + ((size_t)(bhqt*2+1)*128 + qrow)*64 + dc);
  const int bh = bhqt >> 4, qt = bhqt & 15;
  const int b = bh >> 4, h = bh & 15;
  const int tq = qt*128 + qrow;
  u16x4 r;
#pragma unroll
  for (int e=0;e<4;e++) r[e] = f2bf((a[e]*w0 + b4[e]*w1) * inv);
  *(u16x4*)(ao + ((size_t)(b*SEQ + tq))*DIM + h*HD + dc) = r;
}

extern "C" void kernel_launch(void* const* d_in, const int* in_sizes, int n_in,
                              void* d_out, int out_size, void* d_ws, size_t ws_size,
                              hipStream_t stream){
  const float* x     = (const float*)d_in[0];
  const float* Wqkv  = (const float*)d_in[1];
  const float* bqkv  = (const float*)d_in[2];
  const float* Wproj = (const float*)d_in[3];
  const float* bproj = (const float*)d_in[4];
  float* out = (float*)d_out;

  char* ws = (char*)d_ws;
  size_t off = 0;
  auto alloc = [&](size_t bytes)->char*{
    char* p = ws + off; off += (bytes + 255) & ~(size_t)255; return p;
  };
  unsigned short* xb    = (unsigned short*)alloc((size_t)NT*DIM*2);
  unsigned short* wqT   = (unsigned short*)alloc((size_t)N3*DIM*2);
  unsigned short* wpT   = (unsigned short*)alloc((size_t)DIM*DIM*2);
  unsigned short* q_bf  = (unsigned short*)alloc((size_t)NT*DIM*2);
  unsigned short* k_bf  = (unsigned short*)alloc((size_t)NT*DIM*2);
  unsigned short* v_bf  = (unsigned short*)alloc((size_t)NT*DIM*2);
  unsigned short* vT_bf = (unsigned short*)alloc((size_t)NT*DIM*2);
  unsigned short* ao_bf = (unsigned short*)alloc((size_t)NT*DIM*2);
  float*          po    = (float*)alloc((size_t)1024*128*64*sizeof(float));
  float2*         mlb   = (float2*)alloc((size_t)1024*128*sizeof(float2));
  float2*         cstab = (float2*)alloc((size_t)SEQ*32*sizeof(float2));

  k_ropetab<<<SEQ*32/256, 256, 0, stream>>>(cstab);
  k_tobf<<<(NT*DIM/4)/256, 256, 0, stream>>>(x, xb, NT*DIM/4);
  k_transT<<<dim3(N3/32, DIM/32), dim3(32,8), 0, stream>>>(Wqkv, wqT, DIM, N3);
  k_transT<<<dim3(DIM/32, DIM/32), dim3(32,8), 0, stream>>>(Wproj, wpT, DIM, DIM);
  k_gemm<<<dim3(N3/128, NT/128), 256, 0, stream>>>(xb, wqT, bqkv, cstab, q_bf, k_bf, v_bf);
  k_transV<<<dim3(SEQ/64, BATCH*NHEAD), 256, 0, stream>>>(v_bf, vT_bf);
  k_attn<<<dim3(1024), 256, 0, stream>>>(q_bf, k_bf, vT_bf, po, mlb);
  k_comb<<<(65536*16)/256, 256, 0, stream>>>(po, mlb, ao_bf);
  k_gemmP<<<dim3(DIM/64, NT/128), 256, 0, stream>>>(ao_bf, wpT, bproj, out);
}